// Round 7
// baseline (789.233 us; speedup 1.0000x reference)
//
#include <hip/hip_runtime.h>
#include <hip/hip_bf16.h>
#include <hip/hip_fp16.h>

// N=4096 nodes, E=4096 hyperedges, F=256, H=256. All float tensors f32;
// batch_mask int32. out = 8192 f32: [pos_score | neg_score].

typedef short bf16x8 __attribute__((ext_vector_type(8)));
typedef float f32x4 __attribute__((ext_vector_type(4)));
typedef short s16x2 __attribute__((ext_vector_type(2)));
typedef unsigned short u16x2 __attribute__((ext_vector_type(2)));

static __device__ __forceinline__ unsigned short f2bf(float f) {
    __hip_bfloat16 b = __float2bfloat16(f);
    return __builtin_bit_cast(unsigned short, b);
}
static __device__ __forceinline__ float f16u_to_f(unsigned u) {
    __half h = __builtin_bit_cast(__half, (unsigned short)(u & 0xffffu));
    return __half2float(h);
}
static __device__ __forceinline__ unsigned pkmax_i16(unsigned a, unsigned b) {
    s16x2 r = __builtin_elementwise_max(__builtin_bit_cast(s16x2, a), __builtin_bit_cast(s16x2, b));
    return __builtin_bit_cast(unsigned, r);
}
static __device__ __forceinline__ unsigned pkmin_u16(unsigned a, unsigned b) {
    u16x2 r = __builtin_elementwise_min(__builtin_bit_cast(u16x2, a), __builtin_bit_cast(u16x2, b));
    return __builtin_bit_cast(unsigned, r);
}

// ---------------------------------------------------------------- transpose W (f32 -> bf16)
__global__ void k_transpose(const float* __restrict__ Ws, const float* __restrict__ Wh,
                            unsigned short* __restrict__ Wts, unsigned short* __restrict__ Wth) {
    int k = blockIdx.x;
    int n = threadIdx.x;
    const float* W     = blockIdx.y ? Wh : Ws;
    unsigned short* Wt = blockIdx.y ? Wth : Wts;
    Wt[n * 256 + k] = f2bf(W[k * 256 + n]);
}

// ---------------------------------------------------------------- pack mask -> bitwords
// LSB-first (rounds 2-4 proven): bit j of packed[e][w] = mask[e][w*32+j]
__global__ void k_pack_mask(const int* __restrict__ mask, unsigned* __restrict__ packed) {
    int w = blockIdx.x * 256 + threadIdx.x;
    const int* p = mask + (size_t)w * 32;
    unsigned word = 0;
#pragma unroll
    for (int j = 0; j < 32; j += 4) {
        int4 m = *(const int4*)(p + j);
        word |= (m.x != 0 ? (1u << j) : 0u)
              | (m.y != 0 ? (1u << (j + 1)) : 0u)
              | (m.z != 0 ? (1u << (j + 2)) : 0u)
              | (m.w != 0 ? (1u << (j + 3)) : 0u);
    }
    packed[w] = word;
}

// ---------------------------------------------------------------- GEMM + relu -> f16 h
__launch_bounds__(256)
__global__ void k_gemm_relu(const float* __restrict__ pXf, const float* __restrict__ pXm,
                            const float* __restrict__ nXf, const float* __restrict__ nXm,
                            const unsigned short* __restrict__ Wts, const unsigned short* __restrict__ Wth,
                            const float* __restrict__ bs,  const float* __restrict__ bh,
                            unsigned short* __restrict__ hAll /* f16 [2][4096][256] */) {
    const int t  = threadIdx.x;
    const int wv = t >> 6;
    const int l  = t & 63;
    const int lm = l & 15;
    const int q  = l >> 4;
    const int bz = blockIdx.z;
    const float* Xf = bz ? nXf : pXf;
    const float* Xm = bz ? nXm : pXm;
    unsigned short* hb = hAll + (size_t)bz * 4096 * 256;

    const int m0 = blockIdx.x * 64 + wv * 16;
    const int n0 = blockIdx.y * 64;

    f32x4 acc[4] = {};
#pragma unroll
    for (int ks = 0; ks < 512; ks += 32) {
        const float* X           = (ks < 256) ? Xf : Xm;
        const unsigned short* Wt = (ks < 256) ? Wts : Wth;
        const int kk = (ks & 255) + q * 8;
        float4 a0 = *(const float4*)(X + (m0 + lm) * 256 + kk);
        float4 a1 = *(const float4*)(X + (m0 + lm) * 256 + kk + 4);
        bf16x8 a;
        a[0] = (short)f2bf(a0.x); a[1] = (short)f2bf(a0.y);
        a[2] = (short)f2bf(a0.z); a[3] = (short)f2bf(a0.w);
        a[4] = (short)f2bf(a1.x); a[5] = (short)f2bf(a1.y);
        a[6] = (short)f2bf(a1.z); a[7] = (short)f2bf(a1.w);
#pragma unroll
        for (int nt = 0; nt < 4; nt++) {
            bf16x8 b = *(const bf16x8*)(Wt + (n0 + nt * 16 + lm) * 256 + kk);
            acc[nt] = __builtin_amdgcn_mfma_f32_16x16x32_bf16(a, b, acc[nt], 0, 0, 0);
        }
    }
#pragma unroll
    for (int nt = 0; nt < 4; nt++) {
        const int c = n0 + nt * 16 + lm;
        const float bsum = bs[c] + bh[c];
#pragma unroll
        for (int i = 0; i < 4; i++) {
            const int r = m0 + q * 4 + i;
            float v = acc[nt][i] + bsum;
            v = v > 0.f ? v : 0.f;   // relu => h >= +0.0 (u16-monotonic f16 bits)
            hb[r * 256 + c] = __builtin_bit_cast(unsigned short, __float2half(v));
        }
    }
}

// ---------------------------------------------------------------- pool + score
// Block: 8 edges x 256 cols x one branch. 4 waves; wave wv owns edges
// e0+2wv, e0+2wv+1 and scans ALL 4096 nodes (per-wave-complete results --
// NO cross-wave merge). Lane l holds cols 4l..4l+3 as two packed u32.
// Select: nm = ((wd>>j)&1)-1 (member->0 else ~0), SGPR-pinned via
// readfirstlane; t = v|nm: nonmember = 0xFFFF/half -> loses v_pk_max_i16
// (members >= 0) AND v_pk_min_u16 (members <= 0x7C00). 6 VALU per
// (edge,node,256cols wave-wide). h staged through LDS in 64-node chunks
// with register prefetch. Epilogue: in-register dot + shuffle + sigmoid.
// grid (512, 2), block 256. LDS 36 KB -> 4 blocks/CU.
__launch_bounds__(256)
__global__ void k_pool4(const unsigned short* __restrict__ hAll,
                        const unsigned* __restrict__ packed,
                        const float* __restrict__ Wscore,
                        const float* __restrict__ bscore,
                        float* __restrict__ out) {
    __shared__ __align__(16) unsigned bits[8 * 128];     // 4 KB
    __shared__ __align__(16) unsigned hch[64 * 128];     // 32 KB: 64 nodes x 256 cols f16

    const int t  = threadIdx.x;
    const int wv = t >> 6;
    const int l  = t & 63;
    const int e0 = blockIdx.x * 8;
    const int br = blockIdx.y;
    const unsigned short* h = hAll + (size_t)br * 4096 * 256;

    // stage mask bits for 8 edges: 1024 u32 = 256 uint4
    ((uint4*)bits)[t] = ((const uint4*)(packed + e0 * 128))[t];

    unsigned mx0[2], mx1[2], mn0[2], mn1[2];
#pragma unroll
    for (int e = 0; e < 2; e++) {
        mx0[e] = 0x80008000u; mx1[e] = 0x80008000u;
        mn0[e] = 0xFFFFFFFFu; mn1[e] = 0xFFFFFFFFu;
    }

    // prefetch chunk 0: 2048 uint4 per chunk, 8 per thread
    const uint4* hsrc = (const uint4*)h;
    uint4 pre[8];
#pragma unroll
    for (int i = 0; i < 8; i++) pre[i] = hsrc[t + i * 256];

    const int we0 = (wv * 2 + 0) * 128;   // bits row for edge A
    const int we1 = (wv * 2 + 1) * 128;   // bits row for edge B

    for (int ch = 0; ch < 64; ch++) {
        __syncthreads();   // protect LDS from previous iteration's readers
#pragma unroll
        for (int i = 0; i < 8; i++) ((uint4*)hch)[t + i * 256] = pre[i];
        __syncthreads();

        if (ch < 63) {
#pragma unroll
            for (int i = 0; i < 8; i++) pre[i] = hsrc[(ch + 1) * 2048 + t + i * 256];
        }

#pragma unroll
        for (int wl = 0; wl < 2; wl++) {
            const unsigned wd0 = (unsigned)__builtin_amdgcn_readfirstlane((int)bits[we0 + ch * 2 + wl]);
            const unsigned wd1 = (unsigned)__builtin_amdgcn_readfirstlane((int)bits[we1 + ch * 2 + wl]);
#pragma unroll 8
            for (int j = 0; j < 32; j++) {
                uint2 v = *(const uint2*)&hch[(wl * 32 + j) * 128 + 2 * l];
                const unsigned nm0 = (unsigned)__builtin_amdgcn_readfirstlane(
                                         (int)(((wd0 >> j) & 1u) - 1u));
                const unsigned nm1 = (unsigned)__builtin_amdgcn_readfirstlane(
                                         (int)(((wd1 >> j) & 1u) - 1u));
                unsigned a0 = v.x | nm0, a1 = v.y | nm0;
                unsigned b0 = v.x | nm1, b1 = v.y | nm1;
                mx0[0] = pkmax_i16(mx0[0], a0);  mx1[0] = pkmax_i16(mx1[0], a1);
                mn0[0] = pkmin_u16(mn0[0], a0);  mn1[0] = pkmin_u16(mn1[0], a1);
                mx0[1] = pkmax_i16(mx0[1], b0);  mx1[1] = pkmax_i16(mx1[1], b1);
                mn0[1] = pkmin_u16(mn0[1], b0);  mn1[1] = pkmin_u16(mn1[1], b1);
            }
        }
    }

    // epilogue: per-wave-complete; dot + sigmoid, no merge needed
    float4 wsv = *(const float4*)(Wscore + 4 * l);
    const float bsc = *bscore;
#pragma unroll
    for (int e = 0; e < 2; e++) {
        float s = (f16u_to_f(mx0[e])       - f16u_to_f(mn0[e]))       * wsv.x
                + (f16u_to_f(mx0[e] >> 16) - f16u_to_f(mn0[e] >> 16)) * wsv.y
                + (f16u_to_f(mx1[e])       - f16u_to_f(mn1[e]))       * wsv.z
                + (f16u_to_f(mx1[e] >> 16) - f16u_to_f(mn1[e] >> 16)) * wsv.w;
#pragma unroll
        for (int off = 32; off; off >>= 1) s += __shfl_xor(s, off);
        if (l == 0)
            out[br * 4096 + e0 + wv * 2 + e] = 1.f / (1.f + __expf(-(s + bsc)));
    }
}

// ---------------------------------------------------------------- launch
extern "C" void kernel_launch(void* const* d_in, const int* in_sizes, int n_in,
                              void* d_out, int out_size, void* d_ws, size_t ws_size,
                              hipStream_t stream) {
    const float* pf  = (const float*)d_in[0];
    const float* pm  = (const float*)d_in[1];
    const float* nf  = (const float*)d_in[2];
    const float* nm  = (const float*)d_in[3];
    const int*   msk = (const int*)d_in[4];
    const float* Wsf = (const float*)d_in[5];
    const float* bsf = (const float*)d_in[6];
    const float* Whp = (const float*)d_in[7];
    const float* bhp = (const float*)d_in[8];
    const float* Wsc = (const float*)d_in[9];
    const float* bsc = (const float*)d_in[10];
    float* out = (float*)d_out;

    char* ws = (char*)d_ws;
    unsigned short* hbuf = (unsigned short*)ws;                                   // 4 MB
    unsigned short* Wts  = (unsigned short*)(ws + 4u * 1024 * 1024);              // 128 KB
    unsigned short* Wth  = Wts + 256 * 256;                                       // 128 KB
    unsigned*       pck  = (unsigned*)(ws + 4u * 1024 * 1024 + 512u * 1024);      // 2 MB

    k_transpose<<<dim3(256, 2), 256, 0, stream>>>(Wsf, Whp, Wts, Wth);
    k_pack_mask<<<2048, 256, 0, stream>>>(msk, pck);
    k_gemm_relu<<<dim3(64, 4, 2), 256, 0, stream>>>(pf, pm, nf, nm, Wts, Wth, bsf, bhp, hbuf);
    k_pool4<<<dim3(512, 2), 256, 0, stream>>>(hbuf, pck, Wsc, bsc, out);
}

// Round 8
// 560.378 us; speedup vs baseline: 1.4084x; 1.4084x over previous
//
#include <hip/hip_runtime.h>
#include <hip/hip_bf16.h>
#include <hip/hip_fp16.h>

// N=4096 nodes, E=4096 hyperedges, F=256, H=256. All float tensors f32;
// batch_mask int32. out = 8192 f32: [pos_score | neg_score].

typedef short bf16x8 __attribute__((ext_vector_type(8)));
typedef float f32x4 __attribute__((ext_vector_type(4)));
typedef short s16x2 __attribute__((ext_vector_type(2)));
typedef unsigned short u16x2 __attribute__((ext_vector_type(2)));

static __device__ __forceinline__ unsigned short f2bf(float f) {
    __hip_bfloat16 b = __float2bfloat16(f);
    return __builtin_bit_cast(unsigned short, b);
}
static __device__ __forceinline__ float f16u_to_f(unsigned u) {
    __half h = __builtin_bit_cast(__half, (unsigned short)(u & 0xffffu));
    return __half2float(h);
}
static __device__ __forceinline__ unsigned pkmax_i16(unsigned a, unsigned b) {
    s16x2 r = __builtin_elementwise_max(__builtin_bit_cast(s16x2, a), __builtin_bit_cast(s16x2, b));
    return __builtin_bit_cast(unsigned, r);
}
static __device__ __forceinline__ unsigned pkmin_u16(unsigned a, unsigned b) {
    u16x2 r = __builtin_elementwise_min(__builtin_bit_cast(u16x2, a), __builtin_bit_cast(u16x2, b));
    return __builtin_bit_cast(unsigned, r);
}
// async global->LDS DMA, 16B per lane; LDS dest = wave-uniform base + lane*16
static __device__ __forceinline__ void gload_lds16(const void* g, void* l) {
    __builtin_amdgcn_global_load_lds(
        (const __attribute__((address_space(1))) unsigned*)g,
        (__attribute__((address_space(3))) unsigned*)l, 16, 0, 0);
}

// ---------------------------------------------------------------- transpose W (f32 -> bf16)
__global__ void k_transpose(const float* __restrict__ Ws, const float* __restrict__ Wh,
                            unsigned short* __restrict__ Wts, unsigned short* __restrict__ Wth) {
    int k = blockIdx.x;
    int n = threadIdx.x;
    const float* W     = blockIdx.y ? Wh : Ws;
    unsigned short* Wt = blockIdx.y ? Wth : Wts;
    Wt[n * 256 + k] = f2bf(W[k * 256 + n]);
}

// ---------------------------------------------------------------- pack mask -> bitwords
// LSB-first: bit j of packed[e][w] = mask[e][w*32+j]
__global__ void k_pack_mask(const int* __restrict__ mask, unsigned* __restrict__ packed) {
    int w = blockIdx.x * 256 + threadIdx.x;
    const int* p = mask + (size_t)w * 32;
    unsigned word = 0;
#pragma unroll
    for (int j = 0; j < 32; j += 4) {
        int4 m = *(const int4*)(p + j);
        word |= (m.x != 0 ? (1u << j) : 0u)
              | (m.y != 0 ? (1u << (j + 1)) : 0u)
              | (m.z != 0 ? (1u << (j + 2)) : 0u)
              | (m.w != 0 ? (1u << (j + 3)) : 0u);
    }
    packed[w] = word;
}

// ---------------------------------------------------------------- GEMM + relu -> f16 h
__launch_bounds__(256)
__global__ void k_gemm_relu(const float* __restrict__ pXf, const float* __restrict__ pXm,
                            const float* __restrict__ nXf, const float* __restrict__ nXm,
                            const unsigned short* __restrict__ Wts, const unsigned short* __restrict__ Wth,
                            const float* __restrict__ bs,  const float* __restrict__ bh,
                            unsigned short* __restrict__ hAll /* f16 [2][4096][256] */) {
    const int t  = threadIdx.x;
    const int wv = t >> 6;
    const int l  = t & 63;
    const int lm = l & 15;
    const int q  = l >> 4;
    const int bz = blockIdx.z;
    const float* Xf = bz ? nXf : pXf;
    const float* Xm = bz ? nXm : pXm;
    unsigned short* hb = hAll + (size_t)bz * 4096 * 256;

    const int m0 = blockIdx.x * 64 + wv * 16;
    const int n0 = blockIdx.y * 64;

    f32x4 acc[4] = {};
#pragma unroll
    for (int ks = 0; ks < 512; ks += 32) {
        const float* X           = (ks < 256) ? Xf : Xm;
        const unsigned short* Wt = (ks < 256) ? Wts : Wth;
        const int kk = (ks & 255) + q * 8;
        float4 a0 = *(const float4*)(X + (m0 + lm) * 256 + kk);
        float4 a1 = *(const float4*)(X + (m0 + lm) * 256 + kk + 4);
        bf16x8 a;
        a[0] = (short)f2bf(a0.x); a[1] = (short)f2bf(a0.y);
        a[2] = (short)f2bf(a0.z); a[3] = (short)f2bf(a0.w);
        a[4] = (short)f2bf(a1.x); a[5] = (short)f2bf(a1.y);
        a[6] = (short)f2bf(a1.z); a[7] = (short)f2bf(a1.w);
#pragma unroll
        for (int nt = 0; nt < 4; nt++) {
            bf16x8 b = *(const bf16x8*)(Wt + (n0 + nt * 16 + lm) * 256 + kk);
            acc[nt] = __builtin_amdgcn_mfma_f32_16x16x32_bf16(a, b, acc[nt], 0, 0, 0);
        }
    }
#pragma unroll
    for (int nt = 0; nt < 4; nt++) {
        const int c = n0 + nt * 16 + lm;
        const float bsum = bs[c] + bh[c];
#pragma unroll
        for (int i = 0; i < 4; i++) {
            const int r = m0 + q * 4 + i;
            float v = acc[nt][i] + bsum;
            v = v > 0.f ? v : 0.f;   // relu => h >= +0.0 (u16-monotonic f16 bits)
            hb[r * 256 + c] = __builtin_bit_cast(unsigned short, __float2half(v));
        }
    }
}

// ---------------------------------------------------------------- pool + score
// Block: 8 edges x 256 cols x one branch. 4 waves; wave wv owns edges
// e0+2wv, e0+2wv+1 and scans ALL 4096 nodes (per-wave-complete, no merge).
// Lane l holds cols 4l..4l+3 as two packed u32. Select: nm = ((wd>>j)&1)-1
// (member->0 else ~0), SGPR-pinned via readfirstlane; t = v|nm: nonmember =
// 0xFFFF/half -> loses v_pk_max_i16 (members >= 0) AND v_pk_min_u16
// (members <= 0x7C00).
// Staging: 32-node chunks (16 KB) double-buffered via global_load_lds DMA
// (NO VGPR round-trip -> no spill, cf. round-7 1.7 GB scratch traffic).
// Per iteration: barrier (drains prior chunk's DMA), issue next chunk's DMA,
// compute current. grid (512, 2), block 256. LDS 36 KB -> 4 blocks/CU.
__launch_bounds__(256)
__global__ void k_pool5(const unsigned short* __restrict__ hAll,
                        const unsigned* __restrict__ packed,
                        const float* __restrict__ Wscore,
                        const float* __restrict__ bscore,
                        float* __restrict__ out) {
    __shared__ __align__(16) unsigned bits[8 * 128];       // 4 KB
    __shared__ __align__(16) unsigned hch[2][32 * 128];    // 2 x 16 KB

    const int t  = threadIdx.x;
    const int wv = t >> 6;
    const int l  = t & 63;
    const int e0 = blockIdx.x * 8;
    const int br = blockIdx.y;
    const unsigned short* h = hAll + (size_t)br * 4096 * 256;
    const uint4* hsrc = (const uint4*)h;   // 1024 uint4 per 32-node chunk

    // stage mask bits for 8 edges: 1024 u32 = 256 uint4
    ((uint4*)bits)[t] = ((const uint4*)(packed + e0 * 128))[t];

    unsigned mx0[2], mx1[2], mn0[2], mn1[2];
#pragma unroll
    for (int e = 0; e < 2; e++) {
        mx0[e] = 0x80008000u; mx1[e] = 0x80008000u;
        mn0[e] = 0xFFFFFFFFu; mn1[e] = 0xFFFFFFFFu;
    }

    // issue DMA for chunk 0 into buffer 0: wave wv covers uint4 q = wv*256 + i*64 + l
#pragma unroll
    for (int i = 0; i < 4; i++)
        gload_lds16(&hsrc[wv * 256 + i * 64 + l], &hch[0][(wv * 256 + i * 64) * 4]);

    const int we0 = (wv * 2 + 0) * 128;
    const int we1 = (wv * 2 + 1) * 128;

    for (int ch = 0; ch < 128; ch++) {
        const unsigned* buf = hch[ch & 1];
        __syncthreads();   // drains chunk ch's DMA; orders buffer reuse

        if (ch < 127) {    // issue DMA for chunk ch+1 into the other buffer
            unsigned* nb = hch[(ch + 1) & 1];
#pragma unroll
            for (int i = 0; i < 4; i++)
                gload_lds16(&hsrc[(ch + 1) * 1024 + wv * 256 + i * 64 + l],
                            &nb[(wv * 256 + i * 64) * 4]);
        }

        const unsigned wd0 = (unsigned)__builtin_amdgcn_readfirstlane((int)bits[we0 + ch]);
        const unsigned wd1 = (unsigned)__builtin_amdgcn_readfirstlane((int)bits[we1 + ch]);
#pragma unroll
        for (int j = 0; j < 32; j++) {
            uint2 v = *(const uint2*)&buf[j * 128 + 2 * l];
            const unsigned nm0 = (unsigned)__builtin_amdgcn_readfirstlane(
                                     (int)(((wd0 >> j) & 1u) - 1u));
            const unsigned nm1 = (unsigned)__builtin_amdgcn_readfirstlane(
                                     (int)(((wd1 >> j) & 1u) - 1u));
            unsigned a0 = v.x | nm0, a1 = v.y | nm0;
            unsigned b0 = v.x | nm1, b1 = v.y | nm1;
            mx0[0] = pkmax_i16(mx0[0], a0);  mx1[0] = pkmax_i16(mx1[0], a1);
            mn0[0] = pkmin_u16(mn0[0], a0);  mn1[0] = pkmin_u16(mn1[0], a1);
            mx0[1] = pkmax_i16(mx0[1], b0);  mx1[1] = pkmax_i16(mx1[1], b1);
            mn0[1] = pkmin_u16(mn0[1], b0);  mn1[1] = pkmin_u16(mn1[1], b1);
        }
    }

    // epilogue: per-wave-complete; dot + sigmoid
    float4 wsv = *(const float4*)(Wscore + 4 * l);
    const float bsc = *bscore;
#pragma unroll
    for (int e = 0; e < 2; e++) {
        float s = (f16u_to_f(mx0[e])       - f16u_to_f(mn0[e]))       * wsv.x
                + (f16u_to_f(mx0[e] >> 16) - f16u_to_f(mn0[e] >> 16)) * wsv.y
                + (f16u_to_f(mx1[e])       - f16u_to_f(mn1[e]))       * wsv.z
                + (f16u_to_f(mx1[e] >> 16) - f16u_to_f(mn1[e] >> 16)) * wsv.w;
#pragma unroll
        for (int off = 32; off; off >>= 1) s += __shfl_xor(s, off);
        if (l == 0)
            out[br * 4096 + e0 + wv * 2 + e] = 1.f / (1.f + __expf(-(s + bsc)));
    }
}

// ---------------------------------------------------------------- launch
extern "C" void kernel_launch(void* const* d_in, const int* in_sizes, int n_in,
                              void* d_out, int out_size, void* d_ws, size_t ws_size,
                              hipStream_t stream) {
    const float* pf  = (const float*)d_in[0];
    const float* pm  = (const float*)d_in[1];
    const float* nf  = (const float*)d_in[2];
    const float* nm  = (const float*)d_in[3];
    const int*   msk = (const int*)d_in[4];
    const float* Wsf = (const float*)d_in[5];
    const float* bsf = (const float*)d_in[6];
    const float* Whp = (const float*)d_in[7];
    const float* bhp = (const float*)d_in[8];
    const float* Wsc = (const float*)d_in[9];
    const float* bsc = (const float*)d_in[10];
    float* out = (float*)d_out;

    char* ws = (char*)d_ws;
    unsigned short* hbuf = (unsigned short*)ws;                                   // 4 MB
    unsigned short* Wts  = (unsigned short*)(ws + 4u * 1024 * 1024);              // 128 KB
    unsigned short* Wth  = Wts + 256 * 256;                                       // 128 KB
    unsigned*       pck  = (unsigned*)(ws + 4u * 1024 * 1024 + 512u * 1024);      // 2 MB

    k_transpose<<<dim3(256, 2), 256, 0, stream>>>(Wsf, Whp, Wts, Wth);
    k_pack_mask<<<2048, 256, 0, stream>>>(msk, pck);
    k_gemm_relu<<<dim3(64, 4, 2), 256, 0, stream>>>(pf, pm, nf, nm, Wts, Wth, bsf, bhp, hbuf);
    k_pool5<<<dim3(512, 2), 256, 0, stream>>>(hbuf, pck, Wsc, bsc, out);
}